// Round 4
// baseline (438.956 us; speedup 1.0000x reference)
//
#include <hip/hip_runtime.h>

static constexpr int TPB = 256;
static constexpr int SD  = 21;   // state dim
static constexpr int HD  = 64;   // hidden
static constexpr int LT  = 14;   // latent

__device__ __forceinline__ float frcp(float x){ return __builtin_amdgcn_rcpf(x); }
__device__ __forceinline__ float frsq(float x){ return __builtin_amdgcn_rsqf(x); }

__device__ __forceinline__ float ftanh(float x){
    x = fminf(15.0f, fmaxf(-15.0f, x));
    float e = __expf(2.0f * x);
    return (e - 1.0f) * frcp(e + 1.0f);
}

template<int N>
__device__ __forceinline__ void softmax_scale(float (&v)[N], float gate){
    float mx = v[0];
#pragma unroll
    for (int j = 1; j < N; ++j) mx = fmaxf(mx, v[j]);
    float s = 0.0f;
#pragma unroll
    for (int j = 0; j < N; ++j){ v[j] = __expf(v[j] - mx); s += v[j]; }
    float r = frcp(s) * gate;
#pragma unroll
    for (int j = 0; j < N; ++j) v[j] *= r;
}

__global__ __launch_bounds__(TPB, 2) void statenet_v5_kernel(
    const float* __restrict__ state,
    const float* __restrict__ W1,  const float* __restrict__ b1,
    const float* __restrict__ lng, const float* __restrict__ lnb,
    const float* __restrict__ W2,  const float* __restrict__ b2,
    const float* __restrict__ W3,  const float* __restrict__ b3,
    const float* __restrict__ Wd1, const float* __restrict__ bd1,
    const float* __restrict__ Wd2, const float* __restrict__ bd2,
    const float* __restrict__ Wm,  const float* __restrict__ bm,
    const float* __restrict__ Wh,  const float* __restrict__ bh,
    const float* __restrict__ Wc,  const float* __restrict__ bc,
    const float* __restrict__ psm, const float* __restrict__ psh,
    const float* __restrict__ psc,
    float* __restrict__ out, int N)
{
    __shared__ float srow[TPB * SD];     // 21504 B
    const int tid = threadIdx.x;
    const long long row0 = (long long)blockIdx.x * TPB;

    // coalesced stage: 256 rows (21504 B) via float4 (block base is 16B aligned)
    {
        const float4* g  = reinterpret_cast<const float4*>(state + row0 * SD);
        float4*       s4 = reinterpret_cast<float4*>(srow);
        constexpr int NV = TPB * SD / 4;  // 1344
#pragma unroll
        for (int i = 0; i < 6; ++i) {
            int idx = tid + i * TPB;
            if (idx < NV) s4[idx] = g[idx];
        }
    }
    __syncthreads();

    // per-thread row read: stride 21 floats (odd) -> conflict-free 2-way
    float ns[SD];
#pragma unroll
    for (int k = 0; k < SD; ++k) ns[k] = srow[tid * SD + k];

    // _normalize
    ns[0]  *= (1.0f / 3.0f);
    ns[1]  *= (1.0f / 3.0f);
    ns[17] *= 0.5f;
    ns[18] *= 0.25f;
    ns[19]  = fminf(fmaxf(ns[19], 0.0f), 2.0f) * 0.5f;

    // ---- attention heads (k-outer so weight rows are contiguous/uniform) ----
    float m[13], hv[6], cv[4];
#pragma unroll
    for (int j = 0; j < 13; ++j) m[j]  = bm[j];
#pragma unroll
    for (int j = 0; j < 6;  ++j) hv[j] = bh[j];
#pragma unroll
    for (int j = 0; j < 4;  ++j) cv[j] = bc[j];
#pragma unroll
    for (int k = 0; k < SD; ++k) {
        float x = ns[k];
#pragma unroll
        for (int j = 0; j < 13; ++j) m[j]  = fmaf(x, Wm[k * 13 + j], m[j]);
#pragma unroll
        for (int j = 0; j < 6;  ++j) hv[j] = fmaf(x, Wh[k * 6 + j], hv[j]);
#pragma unroll
        for (int j = 0; j < 4;  ++j) cv[j] = fmaf(x, Wc[k * 4 + j], cv[j]);
    }
    const float gm = 2.0f * frcp(1.0f + __expf(-psm[0]));
    const float gh = 2.0f * frcp(1.0f + __expf(-psh[0]));
    const float gc = 2.0f * frcp(1.0f + __expf(-psc[0]));
    softmax_scale<13>(m,  gm);
    softmax_scale<6 >(hv, gh);
    softmax_scale<4 >(cv, gc);

    const long long row = row0 + tid;

    // store metric / hyp / curr now (frees registers for the MLP)
    {
        float* pm = out + (long long)22 * N + row * 13;
#pragma unroll
        for (int j = 0; j < 13; ++j) pm[j] = m[j];
        float* ph = out + (long long)35 * N + row * 6;   // 8B aligned
#pragma unroll
        for (int j = 0; j < 3; ++j)
            reinterpret_cast<float2*>(ph)[j] = make_float2(hv[2 * j], hv[2 * j + 1]);
        float* pc = out + (long long)41 * N + row * 4;   // 16B aligned
        reinterpret_cast<float4*>(pc)[0] = make_float4(cv[0], cv[1], cv[2], cv[3]);
    }

    // attended = ns * metric[EXPAND_IDX]
    constexpr int EIDX[SD] = {0,1,2,3,4,4,5,5,5,6,6,6,7,7,8,9,9,10,10,11,12};
    float at[SD];
#pragma unroll
    for (int k = 0; k < SD; ++k) at[k] = ns[k] * m[EIDX[k]];

    // enc1: [21] @ [21x64]
    float h[HD];
#pragma unroll
    for (int j = 0; j < HD; ++j) h[j] = b1[j];
#pragma unroll
    for (int k = 0; k < SD; ++k) {
        float x = at[k];
#pragma unroll
        for (int j = 0; j < HD; ++j) h[j] = fmaf(x, W1[k * HD + j], h[j]);
    }

    // layernorm + tanh
    float mu = 0.0f;
#pragma unroll
    for (int j = 0; j < HD; ++j) mu += h[j];
    mu *= (1.0f / HD);
    float var = 0.0f;
#pragma unroll
    for (int j = 0; j < HD; ++j) { float d = h[j] - mu; var = fmaf(d, d, var); }
    var *= (1.0f / HD);
    float istd = frsq(var + 1e-5f);
#pragma unroll
    for (int j = 0; j < HD; ++j)
        h[j] = ftanh(fmaf((h[j] - mu) * istd, lng[j], lnb[j]));

    // enc2: [64] @ [64x64] + relu
    float h2[HD];
#pragma unroll
    for (int j = 0; j < HD; ++j) h2[j] = b2[j];
#pragma unroll
    for (int k = 0; k < HD; ++k) {
        float x = h[k];
#pragma unroll
        for (int j = 0; j < HD; ++j) h2[j] = fmaf(x, W2[k * HD + j], h2[j]);
    }
#pragma unroll
    for (int j = 0; j < HD; ++j) h2[j] = fmaxf(h2[j], 0.0f);

    // enc3 -> latent [14]
    float lat[LT];
#pragma unroll
    for (int j = 0; j < LT; ++j) lat[j] = b3[j];
#pragma unroll
    for (int k = 0; k < HD; ++k) {
        float x = h2[k];
#pragma unroll
        for (int j = 0; j < LT; ++j) lat[j] = fmaf(x, W3[k * LT + j], lat[j]);
    }
    {
        float* pl = out + (long long)8 * N + row * 14;   // 8B aligned
#pragma unroll
        for (int j = 0; j < 7; ++j)
            reinterpret_cast<float2*>(pl)[j] = make_float2(lat[2 * j], lat[2 * j + 1]);
    }

    // dec1: [14] @ [14x64] + relu
    float d1[HD];
#pragma unroll
    for (int j = 0; j < HD; ++j) d1[j] = bd1[j];
#pragma unroll
    for (int k = 0; k < LT; ++k) {
        float x = lat[k];
#pragma unroll
        for (int j = 0; j < HD; ++j) d1[j] = fmaf(x, Wd1[k * HD + j], d1[j]);
    }
#pragma unroll
    for (int j = 0; j < HD; ++j) d1[j] = fmaxf(d1[j], 0.0f);

    // dec2 -> corrections [8], tanh
    float c8[8];
#pragma unroll
    for (int j = 0; j < 8; ++j) c8[j] = bd2[j];
#pragma unroll
    for (int k = 0; k < HD; ++k) {
        float x = d1[k];
#pragma unroll
        for (int j = 0; j < 8; ++j) c8[j] = fmaf(x, Wd2[k * 8 + j], c8[j]);
    }
    {
        float* pc = out + row * 8;                       // 16B aligned
        reinterpret_cast<float4*>(pc)[0] =
            make_float4(ftanh(c8[0]), ftanh(c8[1]), ftanh(c8[2]), ftanh(c8[3]));
        reinterpret_cast<float4*>(pc)[1] =
            make_float4(ftanh(c8[4]), ftanh(c8[5]), ftanh(c8[6]), ftanh(c8[7]));
    }
}

extern "C" void kernel_launch(void* const* d_in, const int* in_sizes, int n_in,
                              void* d_out, int out_size, void* d_ws, size_t ws_size,
                              hipStream_t stream)
{
    const float* state = (const float*)d_in[0];
    const float* W1   = (const float*)d_in[1];
    const float* b1   = (const float*)d_in[2];
    const float* lng  = (const float*)d_in[3];
    const float* lnb  = (const float*)d_in[4];
    const float* W2   = (const float*)d_in[5];
    const float* b2   = (const float*)d_in[6];
    const float* W3   = (const float*)d_in[7];
    const float* b3   = (const float*)d_in[8];
    const float* Wd1  = (const float*)d_in[9];
    const float* bd1  = (const float*)d_in[10];
    const float* Wd2  = (const float*)d_in[11];
    const float* bd2  = (const float*)d_in[12];
    const float* Wm   = (const float*)d_in[13];
    const float* bm   = (const float*)d_in[14];
    const float* Wh   = (const float*)d_in[15];
    const float* bh   = (const float*)d_in[16];
    const float* Wc   = (const float*)d_in[17];
    const float* bc   = (const float*)d_in[18];
    const float* psm  = (const float*)d_in[19];
    const float* psh  = (const float*)d_in[20];
    const float* psc  = (const float*)d_in[21];

    const int N = in_sizes[0] / SD;          // 1048576
    dim3 grid((N + TPB - 1) / TPB), block(TPB);
    hipLaunchKernelGGL(statenet_v5_kernel, grid, block, 0, stream,
                       state, W1, b1, lng, lnb, W2, b2, W3, b3,
                       Wd1, bd1, Wd2, bd2, Wm, bm, Wh, bh, Wc, bc,
                       psm, psh, psc, (float*)d_out, N);
}